// Round 3
// baseline (112.778 us; speedup 1.0000x reference)
//
#include <hip/hip_runtime.h>

typedef __attribute__((ext_vector_type(8))) short short8;
typedef __attribute__((ext_vector_type(4))) float f32x4;
typedef unsigned int u32;

#define NB 64
#define NC 3
#define NH 384
#define NW 384
#define NPATCH 576
#define NE 768
#define KDIM 768           // NC*16*16
#define MDIM (NB*NPATCH)   // 36864

#define BM 128
#define BN 128
#define BK 64
#define NBLK_N (NE / BN)   // 6
#define NBLK_M (MDIM / BM) // 288
#define NWG (NBLK_M * NBLK_N)  // 1728
#define NKK (KDIM / BK)    // 12
#define NTHR 512

#define TILE_B_BYTES (BN * BK * 2)                 // 16384
#define WS_B_BYTES (NBLK_N * NKK * TILE_B_BYTES)   // 1,179,648

#define GLOBAL_AS __attribute__((address_space(1)))
#define LDS_AS    __attribute__((address_space(3)))

__device__ __forceinline__ unsigned short f2bf(float f) {
    unsigned int u = __builtin_bit_cast(unsigned int, f);
    u += 0x7fffu + ((u >> 16) & 1u);   // round-to-nearest-even
    return (unsigned short)(u >> 16);
}

// packed f32x2 -> bf16x2 (RNE), 1 VALU inst. No builtin on gfx950 -> inline asm.
__device__ __forceinline__ u32 cvtpk(float lo, float hi) {
    u32 r;
    asm("v_cvt_pk_bf16_f32 %0, %1, %2" : "=v"(r) : "v"(lo), "v"(hi));
    return r;
}

__device__ __forceinline__ void gload_lds16(const void* g, void* l) {
    __builtin_amdgcn_global_load_lds((const GLOBAL_AS u32*)g, (LDS_AS u32*)l, 16, 0, 0);
}

// ---- pre-pass: proj_w fp32 [E][K] -> bf16 tile images with XOR swizzle baked in ----
__global__ __launch_bounds__(256) void convert_w(
    const float* __restrict__ pw, unsigned char* __restrict__ wsb)
{
    int id = blockIdx.x * 256 + threadIdx.x;   // 768*96 = 73728 total
    int e  = id / 96;
    int ck = id - e * 96;          // k-chunk 0..95
    int k0 = ck * 8;

    const float4 f0 = *reinterpret_cast<const float4*>(pw + (size_t)e * KDIM + k0);
    const float4 f1 = *reinterpret_cast<const float4*>(pw + (size_t)e * KDIM + k0 + 4);
    u32 a = (u32)f2bf(f0.x) | ((u32)f2bf(f0.y) << 16);
    u32 b = (u32)f2bf(f0.z) | ((u32)f2bf(f0.w) << 16);
    u32 c = (u32)f2bf(f1.x) | ((u32)f2bf(f1.y) << 16);
    u32 d = (u32)f2bf(f1.z) | ((u32)f2bf(f1.w) << 16);

    int bn = e >> 7;
    int r  = e & 127;
    int kk = k0 >> 6;
    int ch = (k0 & 63) >> 3;
    int off = (bn * NKK + kk) * TILE_B_BYTES + r * 128 + ((ch ^ (r & 7)) * 16);
    *reinterpret_cast<uint4*>(wsb + off) = make_uint4(a, b, c, d);
}

template <bool WSB>
__global__ __launch_bounds__(NTHR, 4) void patch_embed_gemm(
    const float* __restrict__ x,
    const int* __restrict__ start_h,
    const int* __restrict__ start_w,
    const float* __restrict__ pw,
    const float* __restrict__ pb,
    const unsigned char* __restrict__ wsb,
    float* __restrict__ out)
{
    __shared__ __align__(16) unsigned short lA[2][BM * BK];  // 2 x 16 KB, XOR-swizzled
    __shared__ __align__(16) unsigned short lB[2][BN * BK];  // 2 x 16 KB, XOR-swizzled
    __shared__ int baseOff[BM];

    const int tid = threadIdx.x;
    // XCD-aware bijective swizzle (NWG % 8 == 0): the 6 bn-blocks sharing an
    // A-panel become consecutive on ONE XCD -> A-gather served from its L2.
    const int bid  = blockIdx.x;
    const int lbid = (bid & 7) * (NWG / 8) + (bid >> 3);
    const int bm = lbid / NBLK_N;
    const int bn = lbid - bm * NBLK_N;
    const int m0 = bm * BM;
    const int e0 = bn * BN;

    if (tid < BM) {
        int m = m0 + tid;
        int b = m / NPATCH;
        int n = m - b * NPATCH;
        baseOff[tid] = b * (NC * NH * NW) + start_h[b * NPATCH + n] * NW
                     + start_w[b * NPATCH + n];
    }

    const int lane = tid & 63;
    const int wv   = tid >> 6;       // wave 0..7
    const int wr   = wv >> 2;        // wave row 0..1  (64 rows)
    const int wc   = wv & 3;         // wave col 0..3  (32 cols)
    const int lr   = lane & 15;
    const int lk   = lane >> 4;      // 0..3

    // staging decomposition: 16 threads per LDS row, 32 rows per pass, 4 passes
    const int rt = tid >> 4;         // 0..31
    const int j0 = (tid & 15) * 4;   // float index within 64-wide k-slice
    const int chunk  = j0 >> 3;      // 16B chunk index within row (0..7)
    const int within = j0 & 7;
    const int jpart  = (j0 >> 4) * NW + (j0 & 15);  // within-patch part of gather offset

    __syncthreads();

    // per-thread gather bases for its 4 staged rows (element offsets into x)
    int ab[4];
    #pragma unroll
    for (int i = 0; i < 4; ++i) ab[i] = baseOff[i * 32 + rt] + jpart;

    f32x4 acc[4][2] = {};
    float4 areg[4];
    float4 breg[4];

    // ---------- pipeline helpers (macros keep everything in registers) ----------
#define ISSUE_A(KK)                                                          \
    {                                                                        \
        const int koff = ((KK) >> 2) * (NH * NW) + ((KK) & 3) * 4 * NW;      \
        _Pragma("unroll")                                                    \
        for (int i = 0; i < 4; ++i)                                          \
            areg[i] = *reinterpret_cast<const float4*>(x + ab[i] + koff);    \
    }

#define ISSUE_B(KK, BUF)                                                     \
    if (WSB) {                                                               \
        const unsigned char* src = wsb                                       \
            + (size_t)(bn * NKK + (KK)) * TILE_B_BYTES + wv * 2048 + lane * 16; \
        unsigned char* dst = reinterpret_cast<unsigned char*>(lB[BUF]) + wv * 2048; \
        gload_lds16(src, dst);                                               \
        gload_lds16(src + 1024, dst + 1024);                                 \
    } else {                                                                 \
        _Pragma("unroll")                                                    \
        for (int i = 0; i < 4; ++i)                                          \
            breg[i] = *reinterpret_cast<const float4*>(                      \
                pw + (size_t)(e0 + i * 32 + rt) * KDIM + (KK) * BK + j0);    \
    }

#define WRITE_A(BUF)                                                         \
    {                                                                        \
        _Pragma("unroll")                                                    \
        for (int i = 0; i < 4; ++i) {                                        \
            int r = i * 32 + rt;                                             \
            u32 u0 = cvtpk(areg[i].x, areg[i].y);                            \
            u32 u1 = cvtpk(areg[i].z, areg[i].w);                            \
            int off = r * BK + ((chunk ^ (r & 7)) * 8) + within;             \
            *reinterpret_cast<uint2*>(&lA[BUF][off]) = make_uint2(u0, u1);   \
        }                                                                    \
    }

#define WRITE_B(BUF)                                                         \
    if (!WSB) {                                                              \
        _Pragma("unroll")                                                    \
        for (int i = 0; i < 4; ++i) {                                        \
            int r = i * 32 + rt;                                             \
            u32 u0 = cvtpk(breg[i].x, breg[i].y);                            \
            u32 u1 = cvtpk(breg[i].z, breg[i].w);                            \
            int off = r * BK + ((chunk ^ (r & 7)) * 8) + within;             \
            *reinterpret_cast<uint2*>(&lB[BUF][off]) = make_uint2(u0, u1);   \
        }                                                                    \
    }

#define COMPUTE(BUF)                                                         \
    {                                                                        \
        _Pragma("unroll")                                                    \
        for (int ks = 0; ks < 2; ++ks) {                                     \
            short8 af[4], bfr[2];                                            \
            _Pragma("unroll")                                                \
            for (int mi = 0; mi < 4; ++mi) {                                 \
                int row = wr * 64 + mi * 16 + lr;                            \
                int off = row * BK + (((ks * 4 + lk) ^ (row & 7)) * 8);      \
                af[mi] = *reinterpret_cast<const short8*>(&lA[BUF][off]);    \
            }                                                                \
            _Pragma("unroll")                                                \
            for (int ni = 0; ni < 2; ++ni) {                                 \
                int row = wc * 32 + ni * 16 + lr;                            \
                int off = row * BK + (((ks * 4 + lk) ^ (row & 7)) * 8);      \
                bfr[ni] = *reinterpret_cast<const short8*>(&lB[BUF][off]);   \
            }                                                                \
            _Pragma("unroll")                                                \
            for (int mi = 0; mi < 4; ++mi)                                   \
                _Pragma("unroll")                                            \
                for (int ni = 0; ni < 2; ++ni)                               \
                    acc[mi][ni] = __builtin_amdgcn_mfma_f32_16x16x32_bf16(   \
                        af[mi], bfr[ni], acc[mi][ni], 0, 0, 0);              \
        }                                                                    \
    }
    // ---------------------------------------------------------------------------

    // prologue: stage tile 0 into buffer 0
    ISSUE_A(0)
    ISSUE_B(0, 0)
    WRITE_A(0)          // compiler inserts counted vmcnt for areg dependency
    WRITE_B(0)
    __syncthreads();    // drains gload_lds for B(0)

    int buf = 0;
    for (int kk = 0; kk < NKK; ++kk) {
        if (kk + 1 < NKK) {          // issue next tile BEFORE compute (T3 recipe)
            ISSUE_A(kk + 1)
            ISSUE_B(kk + 1, buf ^ 1)
        }
        COMPUTE(buf)
        if (kk + 1 < NKK) {          // convert+write after compute; other buffer
            WRITE_A(buf ^ 1)
            WRITE_B(buf ^ 1)
        }
        __syncthreads();             // one barrier per K-step
        buf ^= 1;
    }

    // ---- epilogue: bias + store ----
    float biasv[2];
    #pragma unroll
    for (int ni = 0; ni < 2; ++ni)
        biasv[ni] = pb[e0 + wc * 32 + ni * 16 + lr];

    #pragma unroll
    for (int mi = 0; mi < 4; ++mi) {
        #pragma unroll
        for (int j = 0; j < 4; ++j) {
            int row = m0 + wr * 64 + mi * 16 + lk * 4 + j;
            float* orow = out + (size_t)row * NE + e0 + wc * 32 + lr;
            #pragma unroll
            for (int ni = 0; ni < 2; ++ni)
                orow[ni * 16] = acc[mi][ni][j] + biasv[ni];
        }
    }
}

extern "C" void kernel_launch(void* const* d_in, const int* in_sizes, int n_in,
                              void* d_out, int out_size, void* d_ws, size_t ws_size,
                              hipStream_t stream) {
    const float* x  = (const float*)d_in[0];
    const int* sh   = (const int*)d_in[1];
    const int* sw   = (const int*)d_in[2];
    const float* pw = (const float*)d_in[3];
    const float* pb = (const float*)d_in[4];
    float* out = (float*)d_out;

    if (ws_size >= (size_t)WS_B_BYTES) {
        unsigned char* wsb = (unsigned char*)d_ws;
        hipLaunchKernelGGL(convert_w, dim3(288), dim3(256), 0, stream, pw, wsb);
        hipLaunchKernelGGL(patch_embed_gemm<true>, dim3(NWG), dim3(NTHR), 0, stream,
                           x, sh, sw, pw, pb, wsb, out);
    } else {
        hipLaunchKernelGGL(patch_embed_gemm<false>, dim3(NWG), dim3(NTHR), 0, stream,
                           x, sh, sw, pw, pb, (const unsigned char*)nullptr, out);
    }
}

// Round 4
// 109.101 us; speedup vs baseline: 1.0337x; 1.0337x over previous
//
#include <hip/hip_runtime.h>

typedef __attribute__((ext_vector_type(8))) short short8;
typedef __attribute__((ext_vector_type(4))) float f32x4;
typedef unsigned int u32;

#define NB 64
#define NC 3
#define NH 384
#define NW 384
#define HW (NH*NW)
#define NPATCH 576
#define NE 768
#define KDIM 768           // NC*16*16
#define MDIM (NB*NPATCH)   // 36864

#define BM 128
#define BN 128
#define BK 32
#define NBLK_N (NE / BN)   // 6
#define NBLK_M (MDIM / BM) // 288
#define NWG (NBLK_M * NBLK_N)  // 1728
#define NKK (KDIM / BK)    // 24

#define TILE_B_BYTES (BN * BK * 2)                 // 8192
#define WS_B_BYTES (NBLK_N * NKK * TILE_B_BYTES)   // 1,179,648

#define GLOBAL_AS __attribute__((address_space(1)))
#define LDS_AS    __attribute__((address_space(3)))

__device__ __forceinline__ unsigned short f2bf(float f) {
    unsigned int u = __builtin_bit_cast(unsigned int, f);
    u += 0x7fffu + ((u >> 16) & 1u);   // round-to-nearest-even
    return (unsigned short)(u >> 16);
}

// packed f32x2 -> bf16x2 (RNE), 1 VALU inst (no builtin on gfx950)
__device__ __forceinline__ u32 cvtpk(float lo, float hi) {
    u32 r;
    asm("v_cvt_pk_bf16_f32 %0, %1, %2" : "=v"(r) : "v"(lo), "v"(hi));
    return r;
}

__device__ __forceinline__ void gload_lds4(const void* g, void* l) {
    __builtin_amdgcn_global_load_lds((const GLOBAL_AS u32*)g, (LDS_AS u32*)l, 4, 0, 0);
}

// ---- pre-pass: proj_w fp32 [E][K] -> bf16 FRAGMENT-ORDER tile images ----
// Tile (bn,kk) = 8KB: slot s (0..511): g=s>>6, l=s&63 holds
// pw[e = bn*128 + g*16 + (l&15)][k = kk*32 + (l>>4)*8 .. +8] as 8 bf16.
// A wave (wc) then reads fragment ni as 1KB contiguous: slot base (wc*4+ni)*64.
__global__ __launch_bounds__(256) void convert_w(
    const float* __restrict__ pw, unsigned char* __restrict__ wsb)
{
    int id = blockIdx.x * 256 + threadIdx.x;   // 6*24*512 = 73728 total
    int tile = id >> 9;            // bn*NKK + kk
    int s    = id & 511;
    int bn = tile / NKK;
    int kk = tile - bn * NKK;
    int g = s >> 6, l = s & 63;
    int e = bn * 128 + g * 16 + (l & 15);
    int k = kk * 32 + (l >> 4) * 8;

    const float4 f0 = *reinterpret_cast<const float4*>(pw + (size_t)e * KDIM + k);
    const float4 f1 = *reinterpret_cast<const float4*>(pw + (size_t)e * KDIM + k + 4);
    u32 a = (u32)f2bf(f0.x) | ((u32)f2bf(f0.y) << 16);
    u32 b = (u32)f2bf(f0.z) | ((u32)f2bf(f0.w) << 16);
    u32 c = (u32)f2bf(f1.x) | ((u32)f2bf(f1.y) << 16);
    u32 d = (u32)f2bf(f1.z) | ((u32)f2bf(f1.w) << 16);
    *reinterpret_cast<uint4*>(wsb + (size_t)tile * TILE_B_BYTES + s * 16) =
        make_uint4(a, b, c, d);
}

template <bool WSB>
__global__ __launch_bounds__(256, 4) void patch_embed_gemm(
    const float* __restrict__ x,
    const int* __restrict__ start_h,
    const int* __restrict__ start_w,
    const float* __restrict__ pw,
    const float* __restrict__ pb,
    const unsigned char* __restrict__ wsb,
    float* __restrict__ out)
{
    // A staged as fp32, double-buffered, XOR-swizzled (chunk ^= row&7 baked
    // into the per-lane SOURCE address; LDS dest stays linear for gload_lds).
    __shared__ __align__(16) float lA[2][BM * BK];   // 2 x 16 KB
    __shared__ int baseOff[BM];

    const int tid = threadIdx.x;
    // XCD-aware bijective swizzle (NWG%8==0): 6 bn-blocks sharing an A-panel
    // run consecutively on one XCD -> gather served from its L2.
    const int bid  = blockIdx.x;
    const int lbid = (bid & 7) * (NWG / 8) + (bid >> 3);
    const int bm = lbid / NBLK_N;
    const int bn = lbid - bm * NBLK_N;
    const int m0 = bm * BM;
    const int e0 = bn * BN;

    if (tid < BM) {
        int m = m0 + tid;
        int b = m / NPATCH;
        int n = m - b * NPATCH;
        baseOff[tid] = b * (NC * HW) + start_h[b * NPATCH + n] * NW
                     + start_w[b * NPATCH + n];
    }

    const int lane = tid & 63;
    const int wv   = tid >> 6;       // wave 0..3
    const int wr   = wv >> 1;        // 0..1 (64 m-rows)
    const int wc   = wv & 1;         // 0..1 (64 e-cols)
    const int lr   = lane & 15;
    const int lk   = lane >> 4;      // 0..3

    __syncthreads();

    // per-lane staging source BYTE offsets (16 gload_lds per wave per tile).
    // Instr i covers LDS rows wv*32 + 2i + (lane>>5); lane's dword-in-row =
    // lane&31 -> physical chunk pc=(lane>>2)&7; stores LOGICAL chunk pc^(r&7).
    int invB[16];
    {
        const int pc = (lane >> 2) & 7;
        const int within = lane & 3;
        #pragma unroll
        for (int i = 0; i < 16; ++i) {
            int r  = wv * 32 + i * 2 + (lane >> 5);
            int lc = pc ^ (r & 7);
            int k  = lc * 4 + within;                 // 0..31 within k-slice
            invB[i] = (baseOff[r] + (k >> 4) * NW + (k & 15)) * 4;
        }
    }

    // per-lane A-fragment LDS byte offsets (physical chunk = logical ^ (r&7))
    int aoff[4];
    #pragma unroll
    for (int mi = 0; mi < 4; ++mi) {
        int r = wr * 64 + mi * 16 + lr;
        aoff[mi] = r * 128 + (((2 * lk) ^ (r & 7)) * 16);
    }

    const unsigned char* btiles = wsb + (size_t)bn * NKK * TILE_B_BYTES;
    const int bvoff = wc * 4096 + lane * 16;

    f32x4 acc[4][4] = {};

#define STAGE_A(KK, BUF)                                                      \
    {                                                                         \
        const char* xk = (const char*)(x + ((KK) >> 3) * HW                   \
                                         + (((KK) & 7) * 2) * NW);            \
        _Pragma("unroll")                                                     \
        for (int i = 0; i < 16; ++i)                                          \
            gload_lds4(xk + invB[i],                                          \
                       (char*)&lA[BUF][0] + (wv * 16 + i) * 256);             \
    }

#define BODY(KK, BUF, DO_STAGE)                                               \
    {                                                                         \
        short8 bfr[4];                                                        \
        if (WSB) {                                                            \
            const unsigned char* bt = btiles + (size_t)(KK) * TILE_B_BYTES    \
                                    + bvoff;                                  \
            _Pragma("unroll")                                                 \
            for (int ni = 0; ni < 4; ++ni)                                    \
                bfr[ni] = __builtin_bit_cast(short8,                          \
                    *reinterpret_cast<const uint4*>(bt + ni * 1024));         \
        } else {                                                              \
            _Pragma("unroll")                                                 \
            for (int ni = 0; ni < 4; ++ni) {                                  \
                int e = e0 + wc * 64 + ni * 16 + lr;                          \
                const float* bp = pw + (size_t)e * KDIM + (KK) * 32 + lk * 8; \
                float4 g0 = *reinterpret_cast<const float4*>(bp);             \
                float4 g1 = *reinterpret_cast<const float4*>(bp + 4);         \
                bfr[ni] = __builtin_bit_cast(short8, make_uint4(              \
                    cvtpk(g0.x, g0.y), cvtpk(g0.z, g0.w),                     \
                    cvtpk(g1.x, g1.y), cvtpk(g1.z, g1.w)));                   \
            }                                                                 \
        }                                                                     \
        if (DO_STAGE) STAGE_A((KK) + 1, (BUF) ^ 1)                            \
        _Pragma("unroll")                                                     \
        for (int mi = 0; mi < 4; ++mi) {                                      \
            const char* base = (const char*)&lA[BUF][0];                      \
            float4 c0 = *reinterpret_cast<const float4*>(base + aoff[mi]);    \
            float4 c1 = *reinterpret_cast<const float4*>(base +               \
                                                         (aoff[mi] ^ 16));    \
            short8 af = __builtin_bit_cast(short8, make_uint4(                \
                cvtpk(c0.x, c0.y), cvtpk(c0.z, c0.w),                         \
                cvtpk(c1.x, c1.y), cvtpk(c1.z, c1.w)));                       \
            _Pragma("unroll")                                                 \
            for (int ni = 0; ni < 4; ++ni)                                    \
                acc[mi][ni] = __builtin_amdgcn_mfma_f32_16x16x32_bf16(        \
                    af, bfr[ni], acc[mi][ni], 0, 0, 0);                       \
        }                                                                     \
        __syncthreads();                                                      \
    }

    // prologue: stage tile 0 into buffer 0
    STAGE_A(0, 0)
    __syncthreads();

    for (int kk = 0; kk < NKK; kk += 2) {
        BODY(kk, 0, true)                       // stages kk+1 -> buf 1
        BODY(kk + 1, 1, (kk + 2 < NKK))         // stages kk+2 -> buf 0
    }

#undef BODY
#undef STAGE_A

    // ---- epilogue: bias + store ----
    float biasv[4];
    #pragma unroll
    for (int ni = 0; ni < 4; ++ni)
        biasv[ni] = pb[e0 + wc * 64 + ni * 16 + lr];

    #pragma unroll
    for (int mi = 0; mi < 4; ++mi) {
        #pragma unroll
        for (int j = 0; j < 4; ++j) {
            int row = m0 + wr * 64 + mi * 16 + lk * 4 + j;
            float* orow = out + (size_t)row * NE + e0 + wc * 64 + lr;
            #pragma unroll
            for (int ni = 0; ni < 4; ++ni)
                orow[ni * 16] = acc[mi][ni][j] + biasv[ni];
        }
    }
}

extern "C" void kernel_launch(void* const* d_in, const int* in_sizes, int n_in,
                              void* d_out, int out_size, void* d_ws, size_t ws_size,
                              hipStream_t stream) {
    const float* x  = (const float*)d_in[0];
    const int* sh   = (const int*)d_in[1];
    const int* sw   = (const int*)d_in[2];
    const float* pw = (const float*)d_in[3];
    const float* pb = (const float*)d_in[4];
    float* out = (float*)d_out;

    if (ws_size >= (size_t)WS_B_BYTES) {
        unsigned char* wsb = (unsigned char*)d_ws;
        hipLaunchKernelGGL(convert_w, dim3(288), dim3(256), 0, stream, pw, wsb);
        hipLaunchKernelGGL(patch_embed_gemm<true>, dim3(NWG), dim3(256), 0, stream,
                           x, sh, sw, pw, pb, wsb, out);
    } else {
        hipLaunchKernelGGL(patch_embed_gemm<false>, dim3(NWG), dim3(256), 0, stream,
                           x, sh, sw, pw, pb, (const unsigned char*)nullptr, out);
    }
}